// Round 1
// baseline (2505.038 us; speedup 1.0000x reference)
//
#include <hip/hip_runtime.h>
#include <math.h>

#define ALPHA 0.1f
#define EPS 1e-6f
#define D 64

// --- degree accumulation: one thread per edge -------------------------------
__global__ void deg_kernel(const int* __restrict__ src, const int* __restrict__ dst,
                           float* __restrict__ outdeg, float* __restrict__ indeg, int E) {
    int e = blockIdx.x * blockDim.x + threadIdx.x;
    if (e < E) {
        atomicAdd(&outdeg[src[e]], 1.0f);
        atomicAdd(&indeg[dst[e]], 1.0f);
    }
}

// --- deg -> clip(deg,1)^-0.5 in place ---------------------------------------
__global__ void norm_kernel(float* __restrict__ sn, float* __restrict__ dn, int n) {
    int i = blockIdx.x * blockDim.x + threadIdx.x;
    if (i < n) {
        sn[i] = 1.0f / sqrtf(fmaxf(sn[i], 1.0f));
        dn[i] = 1.0f / sqrtf(fmaxf(dn[i], 1.0f));
    }
}

// --- feat*src_norm + row L2 norm: one 64-lane wave per row ------------------
__global__ void scale_pn_kernel(const float* __restrict__ in, float* __restrict__ out,
                                const float* __restrict__ sn, float* __restrict__ pn, int n) {
    int row  = blockIdx.x * (blockDim.x >> 6) + (threadIdx.x >> 6);
    int lane = threadIdx.x & 63;
    if (row < n) {
        float s = sn[row];
        float x = in[row * D + lane] * s;
        out[row * D + lane] = x;
        float ss = x * x;
        #pragma unroll
        for (int off = 32; off; off >>= 1) ss += __shfl_xor(ss, off, 64);
        if (lane == 0) pn[row] = sqrtf(ss);
    }
}

// --- edge scatter: one wave per edge, lane = feature dim --------------------
__global__ void scatter_kernel(const float* __restrict__ x, const int* __restrict__ src,
                               const int* __restrict__ dst, float* __restrict__ agg, int E) {
    int e    = blockIdx.x * (blockDim.x >> 6) + (threadIdx.x >> 6);
    int lane = threadIdx.x & 63;
    if (e < E) {
        int s = src[e];
        int t = dst[e];
        float v = x[(long)s * D + lane];
        atomicAdd(&agg[(long)t * D + lane], v);
    }
}

// --- per-row: an, rescale, dst_norm, convex combine with feat0 --------------
__global__ void finalize_kernel(const float* __restrict__ agg, const float* __restrict__ pn,
                                const float* __restrict__ dn, const float* __restrict__ feat0,
                                float* __restrict__ out, int n) {
    int row  = blockIdx.x * (blockDim.x >> 6) + (threadIdx.x >> 6);
    int lane = threadIdx.x & 63;
    if (row < n) {
        float a = agg[row * D + lane];
        float ss = a * a;
        #pragma unroll
        for (int off = 32; off; off >>= 1) ss += __shfl_xor(ss, off, 64);
        float an = sqrtf(ss);
        float scale = pn[row] / (an + EPS) * dn[row];
        float f0 = feat0[row * D + lane];
        out[row * D + lane] = (1.0f - ALPHA) * (a * scale) + ALPHA * f0;
    }
}

extern "C" void kernel_launch(void* const* d_in, const int* in_sizes, int n_in,
                              void* d_out, int out_size, void* d_ws, size_t ws_size,
                              hipStream_t stream) {
    const float* feat = (const float*)d_in[0];
    const int*   src  = (const int*)d_in[1];
    const int*   dst  = (const int*)d_in[2];
    float* out = (float*)d_out;

    int n = in_sizes[0] / D;      // 100000
    int E = in_sizes[1];          // 3200000

    // workspace layout
    float* agg = (float*)d_ws;            // n*D
    float* pn  = agg + (size_t)n * D;     // n
    float* sn  = pn + n;                  // n
    float* dn  = sn + n;                  // n

    // degrees -> norms (sn, dn contiguous)
    hipMemsetAsync(sn, 0, 2 * (size_t)n * sizeof(float), stream);
    deg_kernel<<<(E + 255) / 256, 256, 0, stream>>>(src, dst, sn, dn, E);
    norm_kernel<<<(n + 255) / 256, 256, 0, stream>>>(sn, dn, n);

    const float* cur = feat;
    for (int k = 0; k < 3; ++k) {
        hipMemsetAsync(agg, 0, (size_t)n * D * sizeof(float), stream);
        // scale current feat into d_out (live feat buffer), compute pn
        scale_pn_kernel<<<(n + 3) / 4, 256, 0, stream>>>(cur, out, sn, pn, n);
        // edge scatter-add: wave per edge
        scatter_kernel<<<(E + 3) / 4, 256, 0, stream>>>(out, src, dst, agg, E);
        // finalize row: rescale + dst_norm + convex combine with original feat
        finalize_kernel<<<(n + 3) / 4, 256, 0, stream>>>(agg, pn, dn, feat, out, n);
        cur = out;
    }
}

// Round 2
// 1201.064 us; speedup vs baseline: 2.0857x; 2.0857x over previous
//
#include <hip/hip_runtime.h>
#include <math.h>

#define ALPHA 0.1f
#define EPS 1e-6f
#define D 64

// --- integer degree histogram: one thread per edge --------------------------
__global__ void count_kernel(const int* __restrict__ src, const int* __restrict__ dst,
                             int* __restrict__ odeg, int* __restrict__ ideg, int E) {
    int e = blockIdx.x * blockDim.x + threadIdx.x;
    if (e < E) {
        atomicAdd(&odeg[src[e]], 1);
        atomicAdd(&ideg[dst[e]], 1);
    }
}

// --- deg -> clip(deg,1)^-0.5 ------------------------------------------------
__global__ void norm_kernel(const int* __restrict__ odeg, const int* __restrict__ ideg,
                            float* __restrict__ sn, float* __restrict__ dn, int n) {
    int i = blockIdx.x * blockDim.x + threadIdx.x;
    if (i < n) {
        sn[i] = rsqrtf(fmaxf((float)odeg[i], 1.0f));
        dn[i] = rsqrtf(fmaxf((float)ideg[i], 1.0f));
    }
}

// --- exclusive prefix scan of ideg -> rowptr[0..n], single 1024-thread block
__global__ void scan_kernel(const int* __restrict__ ideg, int* __restrict__ rowptr, int n) {
    __shared__ int partials[1024];
    int tid = threadIdx.x;
    int chunk = (n + 1023) / 1024;
    int start = tid * chunk;
    int end = start + chunk < n ? start + chunk : n;
    int sum = 0;
    for (int i = start; i < end; ++i) sum += ideg[i];
    partials[tid] = sum;
    __syncthreads();
    // Hillis-Steele inclusive scan over partials
    for (int off = 1; off < 1024; off <<= 1) {
        int v = (tid >= off) ? partials[tid - off] : 0;
        __syncthreads();
        partials[tid] += v;
        __syncthreads();
    }
    int running = (tid == 0) ? 0 : partials[tid - 1];  // exclusive
    for (int i = start; i < end; ++i) {
        rowptr[i] = running;
        running += ideg[i];
    }
    if (tid == 1023) rowptr[n] = running;  // == E
}

// --- counting-sort edges by dst: csr_src[pos] = src -------------------------
__global__ void bucket_kernel(const int* __restrict__ src, const int* __restrict__ dst,
                              const int* __restrict__ rowptr, int* __restrict__ cnt,
                              int* __restrict__ csr_src, int E) {
    int e = blockIdx.x * blockDim.x + threadIdx.x;
    if (e < E) {
        int t = dst[e];
        int pos = rowptr[t] + atomicAdd(&cnt[t], 1);
        csr_src[pos] = src[e];
    }
}

// --- one full propagation iteration, fused: one 64-lane wave per dst row ----
// out[row] = (1-a) * (agg * pn/(an+eps) * dn[row]) + a * feat0[row]
// where agg = sum_e cur[src_e]*sn[src_e],  pn = sn[row]*||cur[row]||
__global__ void iter_kernel(const float* __restrict__ cur, const float* __restrict__ feat0,
                            const int* __restrict__ rowptr, const int* __restrict__ csr_src,
                            const float* __restrict__ sn, const float* __restrict__ dn,
                            float* __restrict__ out, int n) {
    int row  = blockIdx.x * (blockDim.x >> 6) + (threadIdx.x >> 6);
    int lane = threadIdx.x & 63;
    if (row >= n) return;

    // prev-x norm: pn = sn[row] * ||cur[row]||
    float x0 = cur[(long)row * D + lane];
    float ss = x0 * x0;
    #pragma unroll
    for (int off = 32; off; off >>= 1) ss += __shfl_xor(ss, off, 64);
    float pn = sn[row] * sqrtf(ss);

    // gather-aggregate over incoming edges
    int beg = rowptr[row], end = rowptr[row + 1];
    float acc = 0.0f;
    for (int base = beg; base < end; base += 64) {
        int m = end - base; if (m > 64) m = 64;
        int   s_l = (lane < m) ? csr_src[base + lane] : 0;
        float w_l = (lane < m) ? sn[s_l] : 0.0f;
        for (int j = 0; j < m; ++j) {
            int   s = __shfl(s_l, j, 64);
            float w = __shfl(w_l, j, 64);
            acc += cur[(long)s * D + lane] * w;
        }
    }

    // agg norm + PNY rescale + dst norm + convex combine
    float aa = acc * acc;
    #pragma unroll
    for (int off = 32; off; off >>= 1) aa += __shfl_xor(aa, off, 64);
    float an = sqrtf(aa);
    float scale = pn / (an + EPS) * dn[row];
    float f0 = feat0[(long)row * D + lane];
    out[(long)row * D + lane] = (1.0f - ALPHA) * (acc * scale) + ALPHA * f0;
}

extern "C" void kernel_launch(void* const* d_in, const int* in_sizes, int n_in,
                              void* d_out, int out_size, void* d_ws, size_t ws_size,
                              hipStream_t stream) {
    const float* feat = (const float*)d_in[0];
    const int*   src  = (const int*)d_in[1];
    const int*   dst  = (const int*)d_in[2];
    float* out = (float*)d_out;

    int n = in_sizes[0] / D;      // 100000
    int E = in_sizes[1];          // 3200000

    // workspace layout (all 4-byte typed)
    int*   odeg    = (int*)d_ws;              // n
    int*   ideg    = odeg + n;                // n
    int*   rowptr  = ideg + n;                // n+1
    int*   cnt     = rowptr + (n + 1);        // n
    int*   csr_src = cnt + n;                 // E
    float* sn      = (float*)(csr_src + E);   // n
    float* dn      = sn + n;                  // n
    float* ws1     = dn + n;                  // n*D

    // zero histograms + counters (odeg, ideg contiguous; cnt separate)
    hipMemsetAsync(odeg, 0, 2 * (size_t)n * sizeof(int), stream);
    hipMemsetAsync(cnt, 0, (size_t)n * sizeof(int), stream);

    count_kernel<<<(E + 255) / 256, 256, 0, stream>>>(src, dst, odeg, ideg, E);
    norm_kernel<<<(n + 255) / 256, 256, 0, stream>>>(odeg, ideg, sn, dn, n);
    scan_kernel<<<1, 1024, 0, stream>>>(ideg, rowptr, n);
    bucket_kernel<<<(E + 255) / 256, 256, 0, stream>>>(src, dst, rowptr, cnt, csr_src, E);

    // 3 fused iterations, ping-pong: feat -> out -> ws1 -> out
    int blocks = (n + 3) / 4;  // 4 waves per 256-thread block
    iter_kernel<<<blocks, 256, 0, stream>>>(feat, feat, rowptr, csr_src, sn, dn, out, n);
    iter_kernel<<<blocks, 256, 0, stream>>>(out,  feat, rowptr, csr_src, sn, dn, ws1, n);
    iter_kernel<<<blocks, 256, 0, stream>>>(ws1,  feat, rowptr, csr_src, sn, dn, out, n);
}

// Round 3
// 877.636 us; speedup vs baseline: 2.8543x; 1.3685x over previous
//
#include <hip/hip_runtime.h>
#include <math.h>

#define ALPHA 0.1f
#define EPS 1e-6f
#define D 64

// --- degree histograms + dst-position record: one thread per edge -----------
__global__ void count_kernel(const int* __restrict__ src, const int* __restrict__ dst,
                             int* __restrict__ odeg, int* __restrict__ ideg,
                             int* __restrict__ pos, int E) {
    int e = blockIdx.x * blockDim.x + threadIdx.x;
    if (e < E) {
        atomicAdd(&odeg[src[e]], 1);
        pos[e] = atomicAdd(&ideg[dst[e]], 1);
    }
}

// --- deg -> clip(deg,1)^-0.5 ------------------------------------------------
__global__ void norm_kernel(const int* __restrict__ odeg, const int* __restrict__ ideg,
                            float* __restrict__ sn, float* __restrict__ dn, int n) {
    int i = blockIdx.x * blockDim.x + threadIdx.x;
    if (i < n) {
        sn[i] = rsqrtf(fmaxf((float)odeg[i], 1.0f));
        dn[i] = rsqrtf(fmaxf((float)ideg[i], 1.0f));
    }
}

// --- exclusive prefix scan of ideg -> rowptr[0..n], single 1024-thread block
__global__ void scan_kernel(const int* __restrict__ ideg, int* __restrict__ rowptr, int n) {
    __shared__ int partials[1024];
    int tid = threadIdx.x;
    int chunk = (n + 1023) / 1024;
    int start = tid * chunk;
    int end = start + chunk < n ? start + chunk : n;
    int sum = 0;
    for (int i = start; i < end; ++i) sum += ideg[i];
    partials[tid] = sum;
    __syncthreads();
    for (int off = 1; off < 1024; off <<= 1) {
        int v = (tid >= off) ? partials[tid - off] : 0;
        __syncthreads();
        partials[tid] += v;
        __syncthreads();
    }
    int running = (tid == 0) ? 0 : partials[tid - 1];  // exclusive
    for (int i = start; i < end; ++i) {
        rowptr[i] = running;
        running += ideg[i];
    }
    if (tid == 1023) rowptr[n] = running;  // == E
}

// --- atomic-free CSR fill: csr_src[rowptr[dst]+pos] = src -------------------
__global__ void place_kernel(const int* __restrict__ src, const int* __restrict__ dst,
                             const int* __restrict__ rowptr, const int* __restrict__ pos,
                             int* __restrict__ csr_src, int E) {
    int e = blockIdx.x * blockDim.x + threadIdx.x;
    if (e < E) {
        csr_src[rowptr[dst[e]] + pos[e]] = src[e];
    }
}

// --- one fused propagation iteration: one 64-lane wave per dst row ----------
// lane = (g,sub): group g (0..3) handles edge subset, sub (0..15) = float4 col
__global__ void iter_kernel(const float* __restrict__ cur,
                            const float4* __restrict__ feat0_4,
                            const int* __restrict__ rowptr, const int* __restrict__ csr_src,
                            const float* __restrict__ sn, const float* __restrict__ dn,
                            float4* __restrict__ out4, int n) {
    int row  = blockIdx.x * (blockDim.x >> 6) + (threadIdx.x >> 6);
    int lane = threadIdx.x & 63;
    if (row >= n) return;
    int g   = lane >> 4;
    int sub = lane & 15;
    const float4* cur4 = (const float4*)cur;

    // prev-x norm: pn = sn[row] * ||cur[row]||
    float x0 = cur[row * D + lane];
    float ss = x0 * x0;
    #pragma unroll
    for (int off = 32; off; off >>= 1) ss += __shfl_xor(ss, off, 64);
    float pn = sn[row] * sqrtf(ss);

    int beg = rowptr[row], end = rowptr[row + 1];
    float4 acc0 = {0.f, 0.f, 0.f, 0.f};
    float4 acc1 = {0.f, 0.f, 0.f, 0.f};
    for (int base = beg; base < end; base += 64) {
        int m = end - base; if (m > 64) m = 64;
        int   s_l = (lane < m) ? csr_src[base + lane] : 0;
        float w_l = (lane < m) ? sn[s_l] : 0.0f;
        int nj = (m + 7) >> 3;  // 8 edges per step: groups handle e0=8j+g, e1=8j+4+g
        for (int j = 0; j < nj; ++j) {
            int e0 = j * 8 + g;
            int e1 = e0 + 4;
            int   s0 = __shfl(s_l, e0, 64);
            float w0 = __shfl(w_l, e0, 64);
            int   s1 = __shfl(s_l, e1, 64);
            float w1 = __shfl(w_l, e1, 64);
            float4 v0 = cur4[(long)s0 * 16 + sub];
            float4 v1 = cur4[(long)s1 * 16 + sub];
            acc0.x += v0.x * w0; acc0.y += v0.y * w0;
            acc0.z += v0.z * w0; acc0.w += v0.w * w0;
            acc1.x += v1.x * w1; acc1.y += v1.y * w1;
            acc1.z += v1.z * w1; acc1.w += v1.w * w1;
        }
    }
    acc0.x += acc1.x; acc0.y += acc1.y; acc0.z += acc1.z; acc0.w += acc1.w;
    // reduce across the 4 edge-groups (lanes differing in bits 4,5)
    #pragma unroll
    for (int off = 16; off <= 32; off <<= 1) {
        acc0.x += __shfl_xor(acc0.x, off, 64);
        acc0.y += __shfl_xor(acc0.y, off, 64);
        acc0.z += __shfl_xor(acc0.z, off, 64);
        acc0.w += __shfl_xor(acc0.w, off, 64);
    }
    // agg L2 norm over the 16 subs
    float dd = acc0.x * acc0.x + acc0.y * acc0.y + acc0.z * acc0.z + acc0.w * acc0.w;
    #pragma unroll
    for (int off = 1; off <= 8; off <<= 1) dd += __shfl_xor(dd, off, 64);
    float an = sqrtf(dd);
    float scale = pn / (an + EPS) * dn[row] * (1.0f - ALPHA);
    if (g == 0) {
        float4 f0 = feat0_4[(long)row * 16 + sub];
        float4 o;
        o.x = acc0.x * scale + ALPHA * f0.x;
        o.y = acc0.y * scale + ALPHA * f0.y;
        o.z = acc0.z * scale + ALPHA * f0.z;
        o.w = acc0.w * scale + ALPHA * f0.w;
        out4[(long)row * 16 + sub] = o;
    }
}

extern "C" void kernel_launch(void* const* d_in, const int* in_sizes, int n_in,
                              void* d_out, int out_size, void* d_ws, size_t ws_size,
                              hipStream_t stream) {
    const float* feat = (const float*)d_in[0];
    const int*   src  = (const int*)d_in[1];
    const int*   dst  = (const int*)d_in[2];
    float* out = (float*)d_out;

    int n = in_sizes[0] / D;      // 100000
    int E = in_sizes[1];          // 3200000

    // workspace layout (4B units); ws1 offset kept 16B-aligned
    int*   odeg    = (int*)d_ws;              // [0, n)
    int*   ideg    = odeg + n;                // [n, 2n)
    int*   rowptr  = ideg + n;                // [2n, 3n+8) (n+1 used, padded)
    float* sn      = (float*)(rowptr + n + 8);// n
    float* dn      = sn + n;                  // n
    int*   csr_src = (int*)(dn + n);          // E
    float* ws1     = (float*)(csr_src + E);   // n*D  (16B-aligned: (5n+8+E)%4==0)
    int*   pos     = (int*)ws1;               // E ints, consumed before iter-2 writes ws1

    hipMemsetAsync(odeg, 0, 2 * (size_t)n * sizeof(int), stream);

    count_kernel<<<(E + 255) / 256, 256, 0, stream>>>(src, dst, odeg, ideg, pos, E);
    norm_kernel<<<(n + 255) / 256, 256, 0, stream>>>(odeg, ideg, sn, dn, n);
    scan_kernel<<<1, 1024, 0, stream>>>(ideg, rowptr, n);
    place_kernel<<<(E + 255) / 256, 256, 0, stream>>>(src, dst, rowptr, pos, csr_src, E);

    // 3 fused iterations, ping-pong: feat -> out -> ws1 -> out
    int blocks = (n + 3) / 4;  // 4 waves per 256-thread block
    iter_kernel<<<blocks, 256, 0, stream>>>(feat, (const float4*)feat, rowptr, csr_src, sn, dn, (float4*)out, n);
    iter_kernel<<<blocks, 256, 0, stream>>>(out,  (const float4*)feat, rowptr, csr_src, sn, dn, (float4*)ws1, n);
    iter_kernel<<<blocks, 256, 0, stream>>>(ws1,  (const float4*)feat, rowptr, csr_src, sn, dn, (float4*)out, n);
}

// Round 4
// 783.222 us; speedup vs baseline: 3.1984x; 1.1205x over previous
//
#include <hip/hip_runtime.h>
#include <hip/hip_fp16.h>
#include <math.h>

#define ALPHA 0.1f
#define EPS 1e-6f
#define D 64

// --- degree histograms + dst-position record: one thread per edge -----------
__global__ void count_kernel(const int* __restrict__ src, const int* __restrict__ dst,
                             int* __restrict__ odeg, int* __restrict__ ideg,
                             int* __restrict__ pos, int E) {
    int e = blockIdx.x * blockDim.x + threadIdx.x;
    if (e < E) {
        atomicAdd(&odeg[src[e]], 1);
        pos[e] = atomicAdd(&ideg[dst[e]], 1);
    }
}

// --- deg -> clip(deg,1)^-0.5 ------------------------------------------------
__global__ void norm_kernel(const int* __restrict__ odeg, const int* __restrict__ ideg,
                            float* __restrict__ sn, float* __restrict__ dn, int n) {
    int i = blockIdx.x * blockDim.x + threadIdx.x;
    if (i < n) {
        sn[i] = rsqrtf(fmaxf((float)odeg[i], 1.0f));
        dn[i] = rsqrtf(fmaxf((float)ideg[i], 1.0f));
    }
}

// --- exclusive prefix scan of ideg -> rowptr[0..n], single 1024-thread block
__global__ void scan_kernel(const int* __restrict__ ideg, int* __restrict__ rowptr, int n) {
    __shared__ int partials[1024];
    int tid = threadIdx.x;
    int chunk = (n + 1023) / 1024;
    int start = tid * chunk;
    int end = start + chunk < n ? start + chunk : n;
    int sum = 0;
    for (int i = start; i < end; ++i) sum += ideg[i];
    partials[tid] = sum;
    __syncthreads();
    for (int off = 1; off < 1024; off <<= 1) {
        int v = (tid >= off) ? partials[tid - off] : 0;
        __syncthreads();
        partials[tid] += v;
        __syncthreads();
    }
    int running = (tid == 0) ? 0 : partials[tid - 1];  // exclusive
    for (int i = start; i < end; ++i) {
        rowptr[i] = running;
        running += ideg[i];
    }
    if (tid == 1023) rowptr[n] = running;  // == E
}

// --- atomic-free CSR fill: csr_src[rowptr[dst]+pos] = src -------------------
__global__ void place_kernel(const int* __restrict__ src, const int* __restrict__ dst,
                             const int* __restrict__ rowptr, const int* __restrict__ pos,
                             int* __restrict__ csr_src, int E) {
    int e = blockIdx.x * blockDim.x + threadIdx.x;
    if (e < E) {
        csr_src[rowptr[dst[e]] + pos[e]] = src[e];
    }
}

// --- seed: scaled_h[row] = feat*sn[row] (f16), pn[row] = sn*||feat[row]|| ---
__global__ void prescale_kernel(const float* __restrict__ feat, const float* __restrict__ sn,
                                __half* __restrict__ outh, float* __restrict__ pn, int n) {
    int row  = blockIdx.x * (blockDim.x >> 6) + (threadIdx.x >> 6);
    int lane = threadIdx.x & 63;
    if (row >= n) return;
    float x = feat[(long)row * D + lane];
    float ss = x * x;
    #pragma unroll
    for (int off = 32; off; off >>= 1) ss += __shfl_xor(ss, off, 64);
    float s = sn[row];
    float v = x * s;
    float vp = __shfl_xor(v, 1, 64);
    if (!(lane & 1)) {
        *(__half2*)(outh + (long)row * D + lane) = __floats2half2_rn(v, vp);
    }
    if (lane == 0) pn[row] = s * sqrtf(ss);
}

// --- fused iteration: one wave per dst row, pure unweighted f16 row sum -----
// lane = (g,sub): g (0..7) = edge slot, sub (0..7) = 16B (8-half) column slice
// inputs pre-scaled by sn; outputs next iter's pre-scaled operand + its pn.
template <int LAST>
__global__ void iter_kernel(const __half* __restrict__ cur, const float* __restrict__ feat0,
                            const int* __restrict__ rowptr, const int* __restrict__ csr_src,
                            const float* __restrict__ pn, const float* __restrict__ dn,
                            const float* __restrict__ sn,
                            __half* __restrict__ nexth, float* __restrict__ npn,
                            float* __restrict__ out, int n) {
    int row  = blockIdx.x * (blockDim.x >> 6) + (threadIdx.x >> 6);
    int lane = threadIdx.x & 63;
    if (row >= n) return;
    int g = lane >> 3, sub = lane & 7;

    float acc[8] = {0.f, 0.f, 0.f, 0.f, 0.f, 0.f, 0.f, 0.f};
    int beg = rowptr[row], end = rowptr[row + 1];
    for (int base = beg; base < end; base += 64) {
        int m = end - base; if (m > 64) m = 64;
        int s_l = (lane < m) ? csr_src[base + lane] : 0;
        int nj = (m + 7) >> 3;
        for (int j = 0; j < nj; ++j) {
            int e = j * 8 + g;
            int s = __shfl(s_l, e, 64);
            if (e < m) {
                int4 raw = *(const int4*)(cur + (long)s * D + sub * 8);
                float2 f0 = __half22float2(*(__half2*)&raw.x);
                float2 f1 = __half22float2(*(__half2*)&raw.y);
                float2 f2 = __half22float2(*(__half2*)&raw.z);
                float2 f3 = __half22float2(*(__half2*)&raw.w);
                acc[0] += f0.x; acc[1] += f0.y;
                acc[2] += f1.x; acc[3] += f1.y;
                acc[4] += f2.x; acc[5] += f2.y;
                acc[6] += f3.x; acc[7] += f3.y;
            }
        }
    }
    // reduce across the 8 edge-groups (lane bits 3..5)
    #pragma unroll
    for (int i = 0; i < 8; ++i) {
        float a = acc[i];
        a += __shfl_xor(a, 8, 64);
        a += __shfl_xor(a, 16, 64);
        a += __shfl_xor(a, 32, 64);
        acc[i] = a;
    }
    // agg L2 norm over the 8 column slices (lane bits 0..2)
    float dd = 0.f;
    #pragma unroll
    for (int i = 0; i < 8; ++i) dd += acc[i] * acc[i];
    dd += __shfl_xor(dd, 1, 64);
    dd += __shfl_xor(dd, 2, 64);
    dd += __shfl_xor(dd, 4, 64);
    float an = sqrtf(dd);
    float scale = pn[row] / (an + EPS) * dn[row] * (1.0f - ALPHA);

    if (g == 0) {
        long fb = (long)row * D + sub * 8;
        float4 f0a = *(const float4*)(feat0 + fb);
        float4 f0b = *(const float4*)(feat0 + fb + 4);
        float nx[8];
        nx[0] = acc[0] * scale + ALPHA * f0a.x;
        nx[1] = acc[1] * scale + ALPHA * f0a.y;
        nx[2] = acc[2] * scale + ALPHA * f0a.z;
        nx[3] = acc[3] * scale + ALPHA * f0a.w;
        nx[4] = acc[4] * scale + ALPHA * f0b.x;
        nx[5] = acc[5] * scale + ALPHA * f0b.y;
        nx[6] = acc[6] * scale + ALPHA * f0b.z;
        nx[7] = acc[7] * scale + ALPHA * f0b.w;
        if (LAST) {
            float4 o0 = {nx[0], nx[1], nx[2], nx[3]};
            float4 o1 = {nx[4], nx[5], nx[6], nx[7]};
            *(float4*)(out + fb) = o0;
            *(float4*)(out + fb + 4) = o1;
        } else {
            float s = sn[row];
            __half2 h0 = __floats2half2_rn(nx[0] * s, nx[1] * s);
            __half2 h1 = __floats2half2_rn(nx[2] * s, nx[3] * s);
            __half2 h2 = __floats2half2_rn(nx[4] * s, nx[5] * s);
            __half2 h3 = __floats2half2_rn(nx[6] * s, nx[7] * s);
            int4 packed;
            packed.x = *(int*)&h0; packed.y = *(int*)&h1;
            packed.z = *(int*)&h2; packed.w = *(int*)&h3;
            *(int4*)(nexth + fb) = packed;
            float nn = 0.f;
            #pragma unroll
            for (int i = 0; i < 8; ++i) nn += nx[i] * nx[i];
            nn += __shfl_xor(nn, 1, 64);
            nn += __shfl_xor(nn, 2, 64);
            nn += __shfl_xor(nn, 4, 64);
            if (sub == 0) npn[row] = s * sqrtf(nn);
        }
    }
}

extern "C" void kernel_launch(void* const* d_in, const int* in_sizes, int n_in,
                              void* d_out, int out_size, void* d_ws, size_t ws_size,
                              hipStream_t stream) {
    const float* feat = (const float*)d_in[0];
    const int*   src  = (const int*)d_in[1];
    const int*   dst  = (const int*)d_in[2];
    float* out = (float*)d_out;

    int n = in_sizes[0] / D;      // 100000
    int E = in_sizes[1];          // 3200000

    // workspace layout (4B units)
    int*   odeg   = (int*)d_ws;               // n
    int*   ideg   = odeg + n;                 // n
    int*   rowptr = ideg + n;                 // n+8 (n+1 used)
    float* sn     = (float*)(rowptr + n + 8); // n
    float* dn     = sn + n;                   // n
    float* pn_a   = dn + n;                   // n
    float* pn_b   = pn_a + n;                 // n
    int*   csr    = (int*)(pn_b + n);         // E
    size_t off4   = 7 * (size_t)n + 8 + E;    // 4B units consumed
    off4 = (off4 + 3) & ~(size_t)3;           // 16B align
    __half* scaled_a = (__half*)((int*)d_ws + off4);   // n*D halves (12.8MB)
    __half* scaled_b = scaled_a + (size_t)n * D;       // n*D halves
    int*    pos      = (int*)scaled_b;                 // E ints, dead after place

    hipMemsetAsync(odeg, 0, 2 * (size_t)n * sizeof(int), stream);

    count_kernel<<<(E + 255) / 256, 256, 0, stream>>>(src, dst, odeg, ideg, pos, E);
    norm_kernel<<<(n + 255) / 256, 256, 0, stream>>>(odeg, ideg, sn, dn, n);
    scan_kernel<<<1, 1024, 0, stream>>>(ideg, rowptr, n);
    place_kernel<<<(E + 255) / 256, 256, 0, stream>>>(src, dst, rowptr, pos, csr, E);

    int blocks = (n + 3) / 4;  // 4 waves per 256-thread block
    prescale_kernel<<<blocks, 256, 0, stream>>>(feat, sn, scaled_a, pn_a, n);
    iter_kernel<0><<<blocks, 256, 0, stream>>>(scaled_a, feat, rowptr, csr, pn_a, dn, sn,
                                               scaled_b, pn_b, nullptr, n);
    iter_kernel<0><<<blocks, 256, 0, stream>>>(scaled_b, feat, rowptr, csr, pn_b, dn, sn,
                                               scaled_a, pn_a, nullptr, n);
    iter_kernel<1><<<blocks, 256, 0, stream>>>(scaled_a, feat, rowptr, csr, pn_a, dn, sn,
                                               nullptr, nullptr, out, n);
}